// Round 9
// baseline (1091.030 us; speedup 1.0000x reference)
//
#include <hip/hip_runtime.h>
#include <hip/hip_cooperative_groups.h>
#include <math.h>

namespace cg = cooperative_groups;

// StreamingDPM: probs = softmax([ -0.5*(D log2pi + logdet_k + quad_nk) + log_prior_k | log_new ])
// N=4096 D=256 K=64, out [N, K+1] fp32.
//
// ws layout (floats):
//   S  : K*D*D  (sweep result; holds -Sigma^{-1} after all steps)
//   cA : K      (log_prior_k - 0.5*(D log2pi + logdet_k))
//   lp : N*K    (log-probs before softmax)
// wv (= S_k * mu_k, [K][D]) lives in the OUTPUT buffer temporarily (quad reads
// it before softmax overwrites out; stream-ordered, safe).
//
// Sweep: ONE cooperative kernel, grid 256 = (k = bid&63, role = bid>>6),
// 512 thr, 1 block/CU (co-resident). Per block step bs:
//   phase A: defer J-cols of step bs-1 (role-striped 64-row chunks, -P^{-1}
//            read from LDS) in parallel with a REDUNDANT register-resident
//            pivot sweep of P_bs in every role's LDS.  grid.sync()
//   phase B: role r != bs applies the trailing update to column slice r
//            (T' = Pl*SJ in LDS, rank-64 update).               grid.sync()
// After bs=3: defer(3), sync, then wv = S*mu (role-striped, coalesced) and
// cA from the register-accumulated logdet. Replaces 10 launches with 1.

#define DD 256
#define KC 64
#define NPTS 4096
#define NT 64
#define BB 64          // sweep block size
#define KG 4           // clusters per quad block
#define CH 8           // S chunk rows staged per quad step
#define NCH (DD / CH)  // 32 chunks

// ---------------- Kernel 1: fully-fused cooperative sweep --------------------
__global__ __launch_bounds__(512) void sweep_coop(
    const float* __restrict__ covs, const float* __restrict__ counts,
    const int* __restrict__ n_points_p, float* __restrict__ S,
    float* __restrict__ cA, const float* __restrict__ means,
    float* __restrict__ wv)
{
  cg::grid_group gg = cg::this_grid();
  const int bid = blockIdx.x;
  const int k = bid & (KC - 1);
  const int ro = bid >> 6;         // role 0..3
  const int tid = threadIdx.x;
  float* Sk = S + (size_t)k * DD * DD;
  const float* Ck = covs + (size_t)k * DD * DD;

  __shared__ __align__(16) float Pl[BB][BB + 4];  // -P^{-1} (row stride 272B = 16B-mult)
  __shared__ __align__(16) float SJ[BB][BB + 4];
  __shared__ __align__(16) float Tl[BB][BB + 4];
  __shared__ __align__(16) float pivc[2][BB];
  __shared__ __align__(16) float pivr[2][BB];

  float ld_acc = 0.0f;  // tid 0 accumulates logdet across all 4 pivots

  const int pr = tid >> 3;         // pivot-sweep row
  const int pc = (tid & 7) * 8;    // pivot-sweep col base

  for (int bs = 0; bs < 5; ++bs) {
    // ---- phase A part 1: deferred write of step bs-1's J columns ----------
    //  M[J,J] = -P^{-1} = Pl ;  M[I,J] = C*P^{-1} = -(C*Pl)
    // (cols J_{bs-1} are disjoint from everything else touched this phase)
    if (bs > 0) {
      const int j0p = (bs - 1) * BB;
      const float* dsrc = (bs == 1) ? Ck : (const float*)Sk;  // C pre-step values
      const int rr = tid >> 3;
      const int cc = (tid & 7) * 8;
      const int r = ro * BB + rr;
      if (ro == bs - 1) {
        // rows in J: direct copy of -P^{-1}
        *reinterpret_cast<float4*>(&Sk[(size_t)r * DD + j0p + cc]) =
            *reinterpret_cast<const float4*>(&Pl[rr][cc]);
        *reinterpret_cast<float4*>(&Sk[(size_t)r * DD + j0p + cc + 4]) =
            *reinterpret_cast<const float4*>(&Pl[rr][cc + 4]);
      } else {
        float Crow[BB];
        #pragma unroll
        for (int p = 0; p < BB; p += 4) {
          float4 cv = *reinterpret_cast<const float4*>(&dsrc[(size_t)r * DD + j0p + p]);
          Crow[p] = cv.x; Crow[p + 1] = cv.y; Crow[p + 2] = cv.z; Crow[p + 3] = cv.w;
        }
        float acc[8] = {0.f, 0.f, 0.f, 0.f, 0.f, 0.f, 0.f, 0.f};
        #pragma unroll
        for (int p = 0; p < BB; ++p) {
          float4 t0 = *reinterpret_cast<const float4*>(&Pl[p][cc]);
          float4 t1 = *reinterpret_cast<const float4*>(&Pl[p][cc + 4]);
          acc[0] = fmaf(Crow[p], t0.x, acc[0]);
          acc[1] = fmaf(Crow[p], t0.y, acc[1]);
          acc[2] = fmaf(Crow[p], t0.z, acc[2]);
          acc[3] = fmaf(Crow[p], t0.w, acc[3]);
          acc[4] = fmaf(Crow[p], t1.x, acc[4]);
          acc[5] = fmaf(Crow[p], t1.y, acc[5]);
          acc[6] = fmaf(Crow[p], t1.z, acc[6]);
          acc[7] = fmaf(Crow[p], t1.w, acc[7]);
        }
        float4 o0 = {-acc[0], -acc[1], -acc[2], -acc[3]};
        float4 o1 = {-acc[4], -acc[5], -acc[6], -acc[7]};
        *reinterpret_cast<float4*>(&Sk[(size_t)r * DD + j0p + cc]) = o0;
        *reinterpret_cast<float4*>(&Sk[(size_t)r * DD + j0p + cc + 4]) = o1;
      }
    }
    if (bs == 4) break;  // final defer done; wv/cA phase follows

    // ---- phase A part 2: register-resident pivot sweep of P_bs ------------
    // (redundant in all 4 roles; leaves Pl = -P^{-1} in this block's LDS)
    {
      const int j0 = bs * BB;
      const float* psrc = (bs == 0) ? Ck : (const float*)Sk;
      float v[8];
      {
        float4 a4 = *reinterpret_cast<const float4*>(&psrc[(size_t)(j0 + pr) * DD + j0 + pc]);
        float4 b4 = *reinterpret_cast<const float4*>(&psrc[(size_t)(j0 + pr) * DD + j0 + pc + 4]);
        v[0] = a4.x; v[1] = a4.y; v[2] = a4.z; v[3] = a4.w;
        v[4] = b4.x; v[5] = b4.y; v[6] = b4.z; v[7] = b4.w;
      }
      if (pc == 0) pivc[0][pr] = v[0];
      if (pr == 0) {
        #pragma unroll
        for (int e = 0; e < 8; ++e) pivr[0][pc + e] = v[e];
      }
      __syncthreads();  // also orders defer's Pl reads before Pl overwrite below

      float ld = 0.0f;
      #pragma unroll 1
      for (int p = 0; p < BB; ++p) {
        const int cur = p & 1, nxt = cur ^ 1;
        const float d = pivc[cur][p];
        const float inv_d = 1.0f / d;
        if (tid == 0) ld += logf(d);
        const float cr = pivc[cur][pr];
        float rw[8];
        *reinterpret_cast<float4*>(&rw[0]) = *reinterpret_cast<const float4*>(&pivr[cur][pc]);
        *reinterpret_cast<float4*>(&rw[4]) = *reinterpret_cast<const float4*>(&pivr[cur][pc + 4]);
        #pragma unroll
        for (int e = 0; e < 8; ++e) {
          float ge = fmaf(-inv_d * cr, rw[e], v[e]);              // general update
          if (pr == p)     ge = rw[e] * inv_d;                    // pivot row
          if (pc + e == p) ge = (pr == p) ? -inv_d : cr * inv_d;  // pivot col/diag
          v[e] = ge;
        }
        if (p < BB - 1) {
          if (pr == p + 1) {
            #pragma unroll
            for (int e = 0; e < 8; ++e) pivr[nxt][pc + e] = v[e];
          }
          if (pc <= p + 1 && p + 1 < pc + 8) pivc[nxt][pr] = v[p + 1 - pc];
        }
        __syncthreads();
      }
      // park -P^{-1} in LDS for phase B and next step's defer
      *reinterpret_cast<float4*>(&Pl[pr][pc]) = *reinterpret_cast<const float4*>(&v[0]);
      *reinterpret_cast<float4*>(&Pl[pr][pc + 4]) = *reinterpret_cast<const float4*>(&v[4]);
      if (tid == 0) ld_acc += ld;
      __syncthreads();  // Pl visible to whole block
    }
    gg.sync();

    // ---- phase B: trailing update of column slice ro (roles != bs) --------
    if (ro != bs) {
      const int c0 = ro * BB;
      const int j0 = bs * BB;
      const float* src = (bs == 0) ? Ck : (const float*)Sk;

      #pragma unroll
      for (int q = 0; q < 8; ++q) {
        int e = q * 512 + tid;
        int r = e >> 6, c = e & 63;
        SJ[r][c] = src[(size_t)(j0 + r) * DD + c0 + c];
      }
      __syncthreads();

      // T' = Pl * SJ  (thread: col c, 8 rows)
      {
        const int c = tid & 63;
        const int rg = (tid >> 6) * 8;
        float tv[8];
        #pragma unroll
        for (int r = 0; r < 8; ++r) tv[r] = 0.0f;
        for (int p = 0; p < BB; p += 4) {
          float s0 = SJ[p][c], s1 = SJ[p + 1][c], s2 = SJ[p + 2][c], s3 = SJ[p + 3][c];
          #pragma unroll
          for (int r = 0; r < 8; ++r) {
            float4 pv = *reinterpret_cast<const float4*>(&Pl[rg + r][p]);
            tv[r] = fmaf(pv.x, s0, fmaf(pv.y, s1, fmaf(pv.z, s2, fmaf(pv.w, s3, tv[r]))));
          }
        }
        #pragma unroll
        for (int r = 0; r < 8; ++r) Tl[rg + r][c] = tv[r];
      }
      __syncthreads();

      // apply (thread: row r, 32 cols)
      const int r = tid & 255;
      const int h = (tid >> 8) * 32;
      const bool inJ = (r >= j0) && (r < j0 + BB);  // wave-uniform
      if (inJ) {
        #pragma unroll
        for (int c = 0; c < 32; c += 4) {
          float4 tv4 = *reinterpret_cast<const float4*>(&Tl[r - j0][h + c]);
          float4 o = {-tv4.x, -tv4.y, -tv4.z, -tv4.w};
          *reinterpret_cast<float4*>(&Sk[(size_t)r * DD + c0 + h + c]) = o;
        }
      } else {
        float Crow[BB];
        #pragma unroll
        for (int p = 0; p < BB; p += 4) {
          float4 cv = *reinterpret_cast<const float4*>(&src[(size_t)r * DD + j0 + p]);
          Crow[p] = cv.x; Crow[p + 1] = cv.y; Crow[p + 2] = cv.z; Crow[p + 3] = cv.w;
        }
        #pragma unroll
        for (int c = 0; c < 32; c += 4) {
          float4 acc = *reinterpret_cast<const float4*>(&src[(size_t)r * DD + c0 + h + c]);
          #pragma unroll
          for (int p = 0; p < BB; ++p) {
            float4 tv4 = *reinterpret_cast<const float4*>(&Tl[p][h + c]);
            acc.x = fmaf(Crow[p], tv4.x, acc.x);
            acc.y = fmaf(Crow[p], tv4.y, acc.y);
            acc.z = fmaf(Crow[p], tv4.z, acc.z);
            acc.w = fmaf(Crow[p], tv4.w, acc.w);
          }
          *reinterpret_cast<float4*>(&Sk[(size_t)r * DD + c0 + h + c]) = acc;
        }
      }
      __syncthreads();  // Tl/SJ free before next step
    }
    gg.sync();
  }
  gg.sync();  // final defer visible everywhere

  // ---- phase W: wv_k = S_k * mu_k (role-striped 64 cols) + cA -------------
  {
    float* muL = &SJ[0][0];
    if (tid < DD) muL[tid] = means[(size_t)k * DD + tid];
    __syncthreads();
    const int jj = tid & 63;
    const int p = tid >> 6;  // 0..7, 32 i's each
    float acc = 0.0f;
    const float* Sc = Sk + (size_t)(p * 32) * DD + ro * BB + jj;
    #pragma unroll 4
    for (int i = 0; i < 32; ++i)
      acc = fmaf(Sc[(size_t)i * DD], muL[p * 32 + i], acc);
    float* red = &Tl[0][0];
    red[p * 64 + jj] = acc;
    __syncthreads();
    if (tid < 64) {
      float t = 0.0f;
      #pragma unroll
      for (int q = 0; q < 8; ++q) t += red[q * 64 + tid];
      wv[(size_t)k * DD + ro * BB + tid] = t;
    }
    if (ro == 0 && tid == 0) {
      float denom = (float)(*n_points_p) + 1.0f;  // ALPHA = 1
      // D*log(2*pi) = 256 * 1.8378770664093453
      cA[k] = logf(counts[k] / denom) - 0.5f * (470.49652900079047f + ld_acc);
    }
  }
}

// ---------------- Kernel 2: quad via mean-folded GEMM (r7 proven form) -------
// dev^T S dev = sum_j (x_j - mu_j) * ((X*S)_nj - wv_j)   (S symmetric).
// 8n x 8j register tile, ONE cluster at a time: per il step 4 ds_read_b128
// feed 64 FMAs (LDS-bound at ~67% VALUBusy; validated r7). KG=4 clusters per
// block. S streamed in CH=8-row chunks, register-prefetched (no spill at the
// 128-VGPR cap). LDS = 64+8+2+1 = 75 KB -> 2 blocks/CU.
__global__ __launch_bounds__(256) void quad_kernel(
    const float* __restrict__ X, const float* __restrict__ means,
    const float* __restrict__ S, const float* __restrict__ cA,
    const float* __restrict__ wv, float* __restrict__ lp)
{
  __shared__ __align__(16) float XT[DD][NT];   // (i,r) at XT[i][r ^ (((i>>2)&15)<<2)]
  __shared__ __align__(16) float Pl[CH * DD];  // S chunk (2048 floats); qred alias
  __shared__ __align__(16) float muw[2][DD];   // mu_k, wv_k
  __shared__ __align__(16) float lpb[KG][NT];  // results, flushed at end

  const int tid = threadIdx.x;
  const int n0 = blockIdx.x * NT;
  const int k0 = blockIdx.y * KG;

  // stage X tile transposed + swizzled (once per block)
  #pragma unroll
  for (int q = 0; q < 16; ++q) {
    int f = q * 1024 + tid * 4;
    int r = f >> 8;
    int c = f & 255;
    float4 xv = *reinterpret_cast<const float4*>(X + (size_t)(n0 + r) * DD + c);
    int rs = r ^ (((c >> 2) & 15) << 2);
    XT[c + 0][rs] = xv.x;
    XT[c + 1][rs] = xv.y;
    XT[c + 2][rs] = xv.z;
    XT[c + 3][rs] = xv.w;
  }

  const int tn = tid & 7;    // n sub-tile: rows tn*8 .. +7
  const int tj = tid >> 3;   // j sub-tile: cols tj*8 .. +7
  const int f0 = tid * 4;
  const int f1 = 1024 + tid * 4;

  #pragma unroll 1
  for (int kk = 0; kk < KG; ++kk) {
    const int k = k0 + kk;
    const float* Sk = S + (size_t)k * DD * DD;

    __syncthreads();  // prev k's qred/muw readers done; XT staged (kk==0)
    muw[0][tid] = means[(size_t)k * DD + tid];
    muw[1][tid] = wv[(size_t)k * DD + tid];

    // prologue: chunk 0 -> registers
    float4 pre0 = *reinterpret_cast<const float4*>(Sk + f0);
    float4 pre1 = *reinterpret_cast<const float4*>(Sk + f1);

    float y[8][8];
    #pragma unroll
    for (int a = 0; a < 8; ++a)
      #pragma unroll
      for (int b = 0; b < 8; ++b) y[a][b] = 0.0f;

    #pragma unroll 1
    for (int ct = 0; ct < NCH; ++ct) {
      __syncthreads();  // Pl free (prev chunk consumed); muw/XT visible
      *reinterpret_cast<float4*>(&Pl[f0]) = pre0;
      *reinterpret_cast<float4*>(&Pl[f1]) = pre1;
      if (ct < NCH - 1) {  // next chunk's loads stay in flight across compute
        const float* srcp = Sk + (size_t)(ct + 1) * CH * DD;
        pre0 = *reinterpret_cast<const float4*>(srcp + f0);
        pre1 = *reinterpret_cast<const float4*>(srcp + f1);
      }
      __syncthreads();  // Pl ready

      #pragma unroll
      for (int il = 0; il < CH; ++il) {
        const int i = ct * CH + il;
        const int sw = ((i >> 2) & 15) << 2;
        float xv[8], pv[8];
        *reinterpret_cast<float4*>(&xv[0]) =
            *reinterpret_cast<const float4*>(&XT[i][(tn * 8) ^ sw]);
        *reinterpret_cast<float4*>(&xv[4]) =
            *reinterpret_cast<const float4*>(&XT[i][(tn * 8 + 4) ^ sw]);
        *reinterpret_cast<float4*>(&pv[0]) =
            *reinterpret_cast<const float4*>(&Pl[il * DD + tj * 8]);
        *reinterpret_cast<float4*>(&pv[4]) =
            *reinterpret_cast<const float4*>(&Pl[il * DD + tj * 8 + 4]);
        #pragma unroll
        for (int a = 0; a < 8; ++a)
          #pragma unroll
          for (int b = 0; b < 8; ++b)
            y[a][b] = fmaf(xv[a], pv[b], y[a][b]);
      }
    }

    // epilogue: q'[n] = sum_j (x[n,j]-mu_j) * (y[n,j]-wv_j), partial over 8 j
    float s[8];
    #pragma unroll
    for (int a = 0; a < 8; ++a) s[a] = 0.0f;
    #pragma unroll
    for (int b = 0; b < 8; ++b) {
      const int j = tj * 8 + b;
      const int swj = ((j >> 2) & 15) << 2;
      float dv[8];
      *reinterpret_cast<float4*>(&dv[0]) =
          *reinterpret_cast<const float4*>(&XT[j][(tn * 8) ^ swj]);
      *reinterpret_cast<float4*>(&dv[4]) =
          *reinterpret_cast<const float4*>(&XT[j][(tn * 8 + 4) ^ swj]);
      const float mj = muw[0][j];
      const float wj = muw[1][j];
      #pragma unroll
      for (int a = 0; a < 8; ++a)
        s[a] = fmaf(dv[a] - mj, y[a][b] - wj, s[a]);
    }

    float* qred = &Pl[0];  // 2048 floats; Pl dead until next k
    __syncthreads();       // all threads' compute reads of Pl done
    *reinterpret_cast<float4*>(&qred[tj * 64 + tn * 8]) =
        *reinterpret_cast<const float4*>(&s[0]);
    *reinterpret_cast<float4*>(&qred[tj * 64 + tn * 8 + 4]) =
        *reinterpret_cast<const float4*>(&s[4]);
    __syncthreads();
    if (tid < 64) {
      float qa = 0.f, qb = 0.f, qc = 0.f, qd = 0.f;
      #pragma unroll
      for (int t = 0; t < 32; t += 4) {
        qa += qred[(t + 0) * 64 + tid];
        qb += qred[(t + 1) * 64 + tid];
        qc += qred[(t + 2) * 64 + tid];
        qd += qred[(t + 3) * 64 + tid];
      }
      // q' = dev^T S dev = -quad  ->  lp = cA + 0.5*q'
      lpb[kk][tid] = fmaf(0.5f, (qa + qb) + (qc + qd), cA[k]);
    }
  }

  // lp flush: one float4 of 4 k-values per point row
  __syncthreads();
  if (tid < 64) {
    float4 o = {lpb[0][tid], lpb[1][tid], lpb[2][tid], lpb[3][tid]};
    *reinterpret_cast<float4*>(&lp[(size_t)(n0 + tid) * KC + k0]) = o;
  }
}

// ---------------- Kernel 3: row softmax over K+1 = 65 entries -----------------
__global__ __launch_bounds__(64) void softmax_kernel(
    const float* __restrict__ lp, const int* __restrict__ n_points_p,
    float* __restrict__ out)
{
  const int n = blockIdx.x;
  const int l = threadIdx.x;
  const float denom = (float)(*n_points_p) + 1.0f;
  const float log_new = -logf(denom);  // log(ALPHA/denom), ALPHA=1

  float v = lp[(size_t)n * KC + l];
  float m = v;
  #pragma unroll
  for (int off = 32; off > 0; off >>= 1) m = fmaxf(m, __shfl_xor(m, off, 64));
  m = fmaxf(m, log_new);

  float e = expf(v - m);
  float s = e;
  #pragma unroll
  for (int off = 32; off > 0; off >>= 1) s += __shfl_xor(s, off, 64);
  float enew = expf(log_new - m);
  s += enew;

  out[(size_t)n * (KC + 1) + l] = e / s;
  if (l == 0) out[(size_t)n * (KC + 1) + KC] = enew / s;
}

extern "C" void kernel_launch(void* const* d_in, const int* in_sizes, int n_in,
                              void* d_out, int out_size, void* d_ws, size_t ws_size,
                              hipStream_t stream)
{
  const float* x       = (const float*)d_in[0];  // [N, D]
  const float* means   = (const float*)d_in[1];  // [K, D]
  const float* covs    = (const float*)d_in[2];  // [K, D, D]
  const float* counts  = (const float*)d_in[3];  // [K]
  const int*   n_points = (const int*)d_in[4];   // scalar

  float* S  = (float*)d_ws;                      // K*D*D
  float* cA = S + (size_t)KC * DD * DD;          // K
  float* lp = cA + KC;                           // N*K
  float* out = (float*)d_out;                    // [N, K+1]
  // wv = S_k*mu_k staged in the out buffer (64KB of 1MB); quad reads it before
  // softmax overwrites out — stream-ordered, safe.
  float* wv = out;

  void* args[] = {(void*)&covs, (void*)&counts, (void*)&n_points,
                  (void*)&S, (void*)&cA, (void*)&means, (void*)&wv};
  hipLaunchCooperativeKernel(sweep_coop, dim3(4 * KC), dim3(512), args, 0, stream);

  quad_kernel<<<dim3(NPTS / NT, KC / KG), 256, 0, stream>>>(x, means, S, cA, wv, lp);
  softmax_kernel<<<NPTS, 64, 0, stream>>>(lp, n_points, out);
}

// Round 10
// 670.650 us; speedup vs baseline: 1.6268x; 1.6268x over previous
//
#include <hip/hip_runtime.h>
#include <math.h>

// StreamingDPM: probs = softmax([ -0.5*(D log2pi + logdet_k + quad_nk) + log_prior_k | log_new ])
// N=4096 D=256 K=64, out [N, K+1] fp32.
//
// ws layout (floats):
//   S    : K*D*D  (sweep result; holds -Sigma^{-1} after all steps)
//   cA   : K      (log_prior_k - 0.5*(D log2pi + logdet_k))
//   ldp  : 4*K    (per-block-step logdet partials)
//   lp   : N*K    (log-probs before softmax; ALIASED as Plbuf during sweep)
// wv (= S_k * mu_k, [K][D]) lives in the OUTPUT buffer temporarily (quad reads
// it before softmax overwrites out; stream-ordered, safe).
//
// Sweep schedule (per block step bs): pivot_kernel grid (K,5):
//   by<4  : deferred J-column writeback of step bs-1 (parallel, 64 rows each)
//   by==4 : register-resident sweep of the 64x64 pivot block (1 barrier/pivot)
// then update_kernel (K,3): trailing update of the 3 non-J column slices.
// (Cooperative single-kernel fusion was tried and measured WORSE: grid.sync()
//  ~70us each on MI355X -> 687us total. Multi-launch chain stays.)

#define DD 256
#define KC 64
#define NPTS 4096
#define NT 64
#define BB 64          // sweep block size
#define KG 4           // clusters per quad block

// ---------------- Kernel 1a: pivot sweep + deferred J-col writeback ----------
__global__ __launch_bounds__(512) void pivot_kernel(
    const float* __restrict__ covs, float* __restrict__ S,
    float* __restrict__ Plbuf, float* __restrict__ ldp, int bs)
{
  const int k = blockIdx.x;
  const int by = blockIdx.y;
  const int tid = threadIdx.x;
  float* Pb = Plbuf + (size_t)k * BB * BB;

  __shared__ __align__(16) float Tl[BB][BB + 4];
  __shared__ __align__(16) float pivc[2][BB];
  __shared__ __align__(16) float pivr[2][BB];

  if (by < 4) {
    // ---- deferred write of step bs-1's J columns (rows r0..r0+63):
    //  M[J,J] = -P^{-1} = Pb ;  M[I,J] = C*P^{-1} = -(C*Pb)
    if (bs == 0) return;
    const int j0p = (bs - 1) * BB;
    const int r0 = by * BB;
    const float* src = ((bs == 1) ? covs : (const float*)S) + (size_t)k * DD * DD;
    float* dst = S + (size_t)k * DD * DD;

    const int rr = tid >> 3;         // 0..63
    const int cc = (tid & 7) * 8;    // 0..56
    *reinterpret_cast<float4*>(&Tl[rr][cc]) =
        *reinterpret_cast<const float4*>(&Pb[rr * BB + cc]);
    *reinterpret_cast<float4*>(&Tl[rr][cc + 4]) =
        *reinterpret_cast<const float4*>(&Pb[rr * BB + cc + 4]);
    __syncthreads();

    const int r = r0 + rr;
    if (r0 == j0p) {
      // rows in J: direct copy of -P^{-1}
      *reinterpret_cast<float4*>(&dst[(size_t)r * DD + j0p + cc]) =
          *reinterpret_cast<const float4*>(&Tl[rr][cc]);
      *reinterpret_cast<float4*>(&dst[(size_t)r * DD + j0p + cc + 4]) =
          *reinterpret_cast<const float4*>(&Tl[rr][cc + 4]);
    } else {
      float Crow[BB];
      #pragma unroll
      for (int p = 0; p < BB; p += 4) {
        float4 cv = *reinterpret_cast<const float4*>(&src[(size_t)r * DD + j0p + p]);
        Crow[p] = cv.x; Crow[p + 1] = cv.y; Crow[p + 2] = cv.z; Crow[p + 3] = cv.w;
      }
      float acc[8] = {0.f, 0.f, 0.f, 0.f, 0.f, 0.f, 0.f, 0.f};
      #pragma unroll
      for (int p = 0; p < BB; ++p) {
        float4 t0 = *reinterpret_cast<const float4*>(&Tl[p][cc]);
        float4 t1 = *reinterpret_cast<const float4*>(&Tl[p][cc + 4]);
        acc[0] = fmaf(Crow[p], t0.x, acc[0]);
        acc[1] = fmaf(Crow[p], t0.y, acc[1]);
        acc[2] = fmaf(Crow[p], t0.z, acc[2]);
        acc[3] = fmaf(Crow[p], t0.w, acc[3]);
        acc[4] = fmaf(Crow[p], t1.x, acc[4]);
        acc[5] = fmaf(Crow[p], t1.y, acc[5]);
        acc[6] = fmaf(Crow[p], t1.z, acc[6]);
        acc[7] = fmaf(Crow[p], t1.w, acc[7]);
      }
      float4 o0 = {-acc[0], -acc[1], -acc[2], -acc[3]};
      float4 o1 = {-acc[4], -acc[5], -acc[6], -acc[7]};
      *reinterpret_cast<float4*>(&dst[(size_t)r * DD + j0p + cc]) = o0;
      *reinterpret_cast<float4*>(&dst[(size_t)r * DD + j0p + cc + 4]) = o1;
    }
    return;
  }

  if (bs == 4) return;  // flush launch: defer blocks only

  // ---- register-resident sweep of P = S[J,J] (step 0: from covs).
  // Thread owns row pr, cols pc..pc+7 in VGPRs for all 64 pivots; only the
  // pivot row/col is exchanged via double-buffered LDS. 1 barrier per pivot.
  const int j0 = bs * BB;
  const float* psrc = ((bs == 0) ? covs : (const float*)S) + (size_t)k * DD * DD;
  const int pr = tid >> 3;
  const int pc = (tid & 7) * 8;

  float v[8];
  {
    float4 a4 = *reinterpret_cast<const float4*>(&psrc[(size_t)(j0 + pr) * DD + j0 + pc]);
    float4 b4 = *reinterpret_cast<const float4*>(&psrc[(size_t)(j0 + pr) * DD + j0 + pc + 4]);
    v[0] = a4.x; v[1] = a4.y; v[2] = a4.z; v[3] = a4.w;
    v[4] = b4.x; v[5] = b4.y; v[6] = b4.z; v[7] = b4.w;
  }
  if (pc == 0) pivc[0][pr] = v[0];
  if (pr == 0) {
    #pragma unroll
    for (int e = 0; e < 8; ++e) pivr[0][pc + e] = v[e];
  }
  __syncthreads();

  float ld = 0.0f;
  #pragma unroll 1
  for (int p = 0; p < BB; ++p) {
    const int cur = p & 1, nxt = cur ^ 1;
    const float d = pivc[cur][p];
    const float inv_d = 1.0f / d;
    if (tid == 0) ld += logf(d);
    const float cr = pivc[cur][pr];
    float rw[8];
    *reinterpret_cast<float4*>(&rw[0]) = *reinterpret_cast<const float4*>(&pivr[cur][pc]);
    *reinterpret_cast<float4*>(&rw[4]) = *reinterpret_cast<const float4*>(&pivr[cur][pc + 4]);
    #pragma unroll
    for (int e = 0; e < 8; ++e) {
      float ge = fmaf(-inv_d * cr, rw[e], v[e]);         // general update
      if (pr == p)     ge = rw[e] * inv_d;               // pivot row
      if (pc + e == p) ge = (pr == p) ? -inv_d : cr * inv_d;  // pivot col/diag
      v[e] = ge;
    }
    if (p < BB - 1) {
      if (pr == p + 1) {
        #pragma unroll
        for (int e = 0; e < 8; ++e) pivr[nxt][pc + e] = v[e];
      }
      if (pc <= p + 1 && p + 1 < pc + 8) pivc[nxt][pr] = v[p + 1 - pc];
    }
    __syncthreads();
  }

  // store -P^{-1} for the update/deferred kernels (coalesced)
  float4 s0 = {v[0], v[1], v[2], v[3]};
  float4 s1 = {v[4], v[5], v[6], v[7]};
  *reinterpret_cast<float4*>(&Pb[pr * BB + pc]) = s0;
  *reinterpret_cast<float4*>(&Pb[pr * BB + pc + 4]) = s1;
  if (tid == 0) ldp[bs * KC + k] = ld;
}

// ---------------- Kernel 1b: trailing update of one non-J column slice ------
__global__ __launch_bounds__(512) void update_kernel(
    const float* __restrict__ covs, float* __restrict__ S,
    const float* __restrict__ Plbuf, int bs)
{
  const int k = blockIdx.x;
  const int si = blockIdx.y;
  const int t = si + (si >= bs ? 1 : 0);
  const int c0 = t * BB;
  const int j0 = bs * BB;
  const int tid = threadIdx.x;
  const float* src = ((bs == 0) ? covs : (const float*)S) + (size_t)k * DD * DD;
  float* dst = S + (size_t)k * DD * DD;

  __shared__ __align__(16) float Pl[BB][BB + 4];
  __shared__ __align__(16) float SJ[BB][BB + 4];
  __shared__ __align__(16) float Tl[BB][BB + 4];

  const float* Pb = Plbuf + (size_t)k * BB * BB;
  #pragma unroll
  for (int q = 0; q < 8; ++q) {
    int e = q * 512 + tid;
    int r = e >> 6, c = e & 63;
    Pl[r][c] = Pb[e];
    SJ[r][c] = src[(size_t)(j0 + r) * DD + c0 + c];
  }
  __syncthreads();

  // ---- T' = Pl * SJ  (thread: col c, 8 rows)
  {
    const int c = tid & 63;
    const int rg = (tid >> 6) * 8;
    float tv[8];
    #pragma unroll
    for (int r = 0; r < 8; ++r) tv[r] = 0.0f;
    for (int p = 0; p < BB; p += 4) {
      float s0 = SJ[p][c], s1 = SJ[p + 1][c], s2 = SJ[p + 2][c], s3 = SJ[p + 3][c];
      #pragma unroll
      for (int r = 0; r < 8; ++r) {
        float4 pv = *reinterpret_cast<const float4*>(&Pl[rg + r][p]);
        tv[r] = fmaf(pv.x, s0, fmaf(pv.y, s1, fmaf(pv.z, s2, fmaf(pv.w, s3, tv[r]))));
      }
    }
    #pragma unroll
    for (int r = 0; r < 8; ++r) Tl[rg + r][c] = tv[r];
  }
  __syncthreads();

  // ---- apply to this column slice (thread: row r, 32 cols)
  const int r = tid & 255;
  const int h = (tid >> 8) * 32;
  const bool inJ = (r >= j0) && (r < j0 + BB);  // wave-uniform
  if (inJ) {
    #pragma unroll
    for (int c = 0; c < 32; c += 4) {
      float4 tv4 = *reinterpret_cast<const float4*>(&Tl[r - j0][h + c]);
      float4 o = {-tv4.x, -tv4.y, -tv4.z, -tv4.w};
      *reinterpret_cast<float4*>(&dst[(size_t)r * DD + c0 + h + c]) = o;
    }
  } else {
    float Crow[BB];
    #pragma unroll
    for (int p = 0; p < BB; p += 4) {
      float4 cv = *reinterpret_cast<const float4*>(&src[(size_t)r * DD + j0 + p]);
      Crow[p] = cv.x; Crow[p + 1] = cv.y; Crow[p + 2] = cv.z; Crow[p + 3] = cv.w;
    }
    #pragma unroll
    for (int c = 0; c < 32; c += 4) {
      float4 acc = *reinterpret_cast<const float4*>(&src[(size_t)r * DD + c0 + h + c]);
      #pragma unroll
      for (int p = 0; p < BB; ++p) {
        float4 tv4 = *reinterpret_cast<const float4*>(&Tl[p][h + c]);
        acc.x = fmaf(Crow[p], tv4.x, acc.x);
        acc.y = fmaf(Crow[p], tv4.y, acc.y);
        acc.z = fmaf(Crow[p], tv4.z, acc.z);
        acc.w = fmaf(Crow[p], tv4.w, acc.w);
      }
      *reinterpret_cast<float4*>(&dst[(size_t)r * DD + c0 + h + c]) = acc;
    }
  }
}

// ---------------- Kernel 1c: wv_k = S_k * mu_k ; cA assembly -----------------
__global__ __launch_bounds__(256) void w_kernel(
    const float* __restrict__ S, const float* __restrict__ means,
    const float* __restrict__ counts, const int* __restrict__ n_points_p,
    const float* __restrict__ ldp, float* __restrict__ cA,
    float* __restrict__ wv)
{
  const int k = blockIdx.x;
  const int tid = threadIdx.x;
  if (tid == 0) {
    float denom = (float)(*n_points_p) + 1.0f;  // ALPHA = 1
    float ld = ldp[k] + ldp[KC + k] + ldp[2 * KC + k] + ldp[3 * KC + k];
    // D*log(2*pi) = 256 * 1.8378770664093453
    cA[k] = logf(counts[k] / denom) - 0.5f * (470.49652900079047f + ld);
  }
  const float* Sk = S + (size_t)k * DD * DD;
  __shared__ float mus[DD];
  mus[tid] = means[(size_t)k * DD + tid];
  __syncthreads();
  float a0 = 0.f, a1 = 0.f, a2 = 0.f, a3 = 0.f;
  for (int j = 0; j < DD; j += 4) {
    a0 = fmaf(Sk[(size_t)(j + 0) * DD + tid], mus[j + 0], a0);
    a1 = fmaf(Sk[(size_t)(j + 1) * DD + tid], mus[j + 1], a1);
    a2 = fmaf(Sk[(size_t)(j + 2) * DD + tid], mus[j + 2], a2);
    a3 = fmaf(Sk[(size_t)(j + 3) * DD + tid], mus[j + 3], a3);
  }
  wv[(size_t)k * DD + tid] = (a0 + a1) + (a2 + a3);
}

// ---------------- Kernel 2: quad via mean-folded GEMM, hybrid S sourcing -----
// dev^T S dev = sum_j (x_j - mu_j) * ((X*S)_nj - wv_j)   (S symmetric).
// 8n x 8j register tile. HYBRID S path: EVEN rows staged in LDS (4-row chunks,
// register-prefetched), ODD rows' per-thread 32B slices read from global/L2
// with a 2-row-deep register pipeline (prefetch distance ~512 VALU cyc >>
// ~200 cyc L2 latency; r8's 1-deep all-global was latency-bound at 59%).
// Per il-pair per CU: LDS = 8 waves x ~6.25 b128 x 12 ~ 600 cyc vs SIMD 512
// -> VALUBusy ~82% (r7 all-LDS: 384 vs 256/il -> 67%). ~115 live VGPR, no
// spill. LDS = 64+4+2+1+8 = 79 KB -> 2 blocks/CU.
__global__ __launch_bounds__(256) void quad_kernel(
    const float* __restrict__ X, const float* __restrict__ means,
    const float* __restrict__ S, const float* __restrict__ cA,
    const float* __restrict__ wv, float* __restrict__ lp)
{
  __shared__ __align__(16) float XT[DD][NT];    // (i,r) at XT[i][r ^ (((i>>2)&15)<<2)]
  __shared__ __align__(16) float Pl[4 * DD];    // even rows of current chunk
  __shared__ __align__(16) float muw[2][DD];    // mu_k, wv_k
  __shared__ __align__(16) float lpb[KG][NT];   // results, flushed at end
  __shared__ __align__(16) float qred[32 * NT]; // 8 KB reduction buffer

  const int tid = threadIdx.x;
  const int n0 = blockIdx.x * NT;
  const int k0 = blockIdx.y * KG;

  // stage X tile transposed + swizzled (once per block)
  #pragma unroll
  for (int q = 0; q < 16; ++q) {
    int f = q * 1024 + tid * 4;
    int r = f >> 8;
    int c = f & 255;
    float4 xv = *reinterpret_cast<const float4*>(X + (size_t)(n0 + r) * DD + c);
    int rs = r ^ (((c >> 2) & 15) << 2);
    XT[c + 0][rs] = xv.x;
    XT[c + 1][rs] = xv.y;
    XT[c + 2][rs] = xv.z;
    XT[c + 3][rs] = xv.w;
  }

  const int tn = tid & 7;    // n sub-tile: rows tn*8 .. +7
  const int tj = tid >> 3;   // j sub-tile: cols tj*8 .. +7
  const int sq = tid >> 6;   // staging row-within-chunk (even row 2*sq)
  const int sc = (tid * 4) & 255;  // staging col

  #pragma unroll 1
  for (int kk = 0; kk < KG; ++kk) {
    const int k = k0 + kk;
    const float* Sk = S + (size_t)k * DD * DD;
    const float* Skj = Sk + tj * 8;  // thread's odd-row j-slice base

    __syncthreads();  // prev k's qred/muw readers done; XT staged (kk==0)
    muw[0][tid] = means[(size_t)k * DD + tid];
    muw[1][tid] = wv[(size_t)k * DD + tid];

    // prologue: chunk-0 even rows -> register; odd rows 1,3 -> pipeline regs
    float4 pre = *reinterpret_cast<const float4*>(Sk + (size_t)(2 * sq) * DD + sc);
    float ov0[8], ov1[8];
    *reinterpret_cast<float4*>(&ov0[0]) = *reinterpret_cast<const float4*>(Skj + 1 * DD);
    *reinterpret_cast<float4*>(&ov0[4]) = *reinterpret_cast<const float4*>(Skj + 1 * DD + 4);
    *reinterpret_cast<float4*>(&ov1[0]) = *reinterpret_cast<const float4*>(Skj + 3 * DD);
    *reinterpret_cast<float4*>(&ov1[4]) = *reinterpret_cast<const float4*>(Skj + 3 * DD + 4);

    float y[8][8];
    #pragma unroll
    for (int a = 0; a < 8; ++a)
      #pragma unroll
      for (int b = 0; b < 8; ++b) y[a][b] = 0.0f;

    #pragma unroll 1
    for (int ct = 0; ct < 32; ++ct) {
      __syncthreads();  // Pl free (prev chunk consumed); muw/XT visible
      *reinterpret_cast<float4*>(&Pl[tid * 4]) = pre;
      if (ct < 31) {    // next chunk's even rows stay in flight across compute
        pre = *reinterpret_cast<const float4*>(
            Sk + (size_t)((ct + 1) * 8 + 2 * sq) * DD + sc);
      }
      __syncthreads();  // Pl ready

      #pragma unroll
      for (int q = 0; q < 4; ++q) {
        const int ie = ct * 8 + 2 * q;
        // ---- even row: pv from LDS
        {
          const int sw = ((ie >> 2) & 15) << 2;
          float xv[8], pv[8];
          *reinterpret_cast<float4*>(&xv[0]) =
              *reinterpret_cast<const float4*>(&XT[ie][(tn * 8) ^ sw]);
          *reinterpret_cast<float4*>(&xv[4]) =
              *reinterpret_cast<const float4*>(&XT[ie][(tn * 8 + 4) ^ sw]);
          *reinterpret_cast<float4*>(&pv[0]) =
              *reinterpret_cast<const float4*>(&Pl[q * DD + tj * 8]);
          *reinterpret_cast<float4*>(&pv[4]) =
              *reinterpret_cast<const float4*>(&Pl[q * DD + tj * 8 + 4]);
          #pragma unroll
          for (int a = 0; a < 8; ++a)
            #pragma unroll
            for (int b = 0; b < 8; ++b)
              y[a][b] = fmaf(xv[a], pv[b], y[a][b]);
        }
        // ---- odd row: pv from the 2-deep global pipeline
        {
          const int io = ie + 1;
          const int sw = ((io >> 2) & 15) << 2;
          float xv[8];
          *reinterpret_cast<float4*>(&xv[0]) =
              *reinterpret_cast<const float4*>(&XT[io][(tn * 8) ^ sw]);
          *reinterpret_cast<float4*>(&xv[4]) =
              *reinterpret_cast<const float4*>(&XT[io][(tn * 8 + 4) ^ sw]);
          int inx = io + 4;                 // row consumed 2 odd-steps later
          if (inx > 255) inx = 255;         // clamped tail load (unused)
          const float* np = Skj + (size_t)inx * DD;
          if ((q & 1) == 0) {
            #pragma unroll
            for (int a = 0; a < 8; ++a)
              #pragma unroll
              for (int b = 0; b < 8; ++b)
                y[a][b] = fmaf(xv[a], ov0[b], y[a][b]);
            *reinterpret_cast<float4*>(&ov0[0]) = *reinterpret_cast<const float4*>(np);
            *reinterpret_cast<float4*>(&ov0[4]) = *reinterpret_cast<const float4*>(np + 4);
          } else {
            #pragma unroll
            for (int a = 0; a < 8; ++a)
              #pragma unroll
              for (int b = 0; b < 8; ++b)
                y[a][b] = fmaf(xv[a], ov1[b], y[a][b]);
            *reinterpret_cast<float4*>(&ov1[0]) = *reinterpret_cast<const float4*>(np);
            *reinterpret_cast<float4*>(&ov1[4]) = *reinterpret_cast<const float4*>(np + 4);
          }
        }
      }
    }

    // epilogue: q'[n] = sum_j (x[n,j]-mu_j) * (y[n,j]-wv_j), partial over 8 j
    float s[8];
    #pragma unroll
    for (int a = 0; a < 8; ++a) s[a] = 0.0f;
    #pragma unroll
    for (int b = 0; b < 8; ++b) {
      const int j = tj * 8 + b;
      const int swj = ((j >> 2) & 15) << 2;
      float dv[8];
      *reinterpret_cast<float4*>(&dv[0]) =
          *reinterpret_cast<const float4*>(&XT[j][(tn * 8) ^ swj]);
      *reinterpret_cast<float4*>(&dv[4]) =
          *reinterpret_cast<const float4*>(&XT[j][(tn * 8 + 4) ^ swj]);
      const float mj = muw[0][j];
      const float wj = muw[1][j];
      #pragma unroll
      for (int a = 0; a < 8; ++a)
        s[a] = fmaf(dv[a] - mj, y[a][b] - wj, s[a]);
    }

    *reinterpret_cast<float4*>(&qred[tj * 64 + tn * 8]) =
        *reinterpret_cast<const float4*>(&s[0]);
    *reinterpret_cast<float4*>(&qred[tj * 64 + tn * 8 + 4]) =
        *reinterpret_cast<const float4*>(&s[4]);
    __syncthreads();
    if (tid < 64) {
      float qa = 0.f, qb = 0.f, qc = 0.f, qd = 0.f;
      #pragma unroll
      for (int t = 0; t < 32; t += 4) {
        qa += qred[(t + 0) * 64 + tid];
        qb += qred[(t + 1) * 64 + tid];
        qc += qred[(t + 2) * 64 + tid];
        qd += qred[(t + 3) * 64 + tid];
      }
      // q' = dev^T S dev = -quad  ->  lp = cA + 0.5*q'
      lpb[kk][tid] = fmaf(0.5f, (qa + qb) + (qc + qd), cA[k]);
    }
  }

  // lp flush: one float4 of 4 k-values per point row
  __syncthreads();
  if (tid < 64) {
    float4 o = {lpb[0][tid], lpb[1][tid], lpb[2][tid], lpb[3][tid]};
    *reinterpret_cast<float4*>(&lp[(size_t)(n0 + tid) * KC + k0]) = o;
  }
}

// ---------------- Kernel 3: row softmax over K+1 = 65 entries -----------------
__global__ __launch_bounds__(64) void softmax_kernel(
    const float* __restrict__ lp, const int* __restrict__ n_points_p,
    float* __restrict__ out)
{
  const int n = blockIdx.x;
  const int l = threadIdx.x;
  const float denom = (float)(*n_points_p) + 1.0f;
  const float log_new = -logf(denom);  // log(ALPHA/denom), ALPHA=1

  float v = lp[(size_t)n * KC + l];
  float m = v;
  #pragma unroll
  for (int off = 32; off > 0; off >>= 1) m = fmaxf(m, __shfl_xor(m, off, 64));
  m = fmaxf(m, log_new);

  float e = expf(v - m);
  float s = e;
  #pragma unroll
  for (int off = 32; off > 0; off >>= 1) s += __shfl_xor(s, off, 64);
  float enew = expf(log_new - m);
  s += enew;

  out[(size_t)n * (KC + 1) + l] = e / s;
  if (l == 0) out[(size_t)n * (KC + 1) + KC] = enew / s;
}

extern "C" void kernel_launch(void* const* d_in, const int* in_sizes, int n_in,
                              void* d_out, int out_size, void* d_ws, size_t ws_size,
                              hipStream_t stream)
{
  const float* x       = (const float*)d_in[0];  // [N, D]
  const float* means   = (const float*)d_in[1];  // [K, D]
  const float* covs    = (const float*)d_in[2];  // [K, D, D]
  const float* counts  = (const float*)d_in[3];  // [K]
  const int*   n_points = (const int*)d_in[4];   // scalar

  float* S   = (float*)d_ws;                      // K*D*D
  float* cA  = S + (size_t)KC * DD * DD;          // K
  float* ldp = cA + KC;                           // 4*K
  float* lp  = ldp + 4 * KC;                      // N*K
  float* Plbuf = lp;  // alias: Plbuf (K*64*64 = N*K floats) used only during
                      // sweep; lp written only by quad afterwards.
  float* out = (float*)d_out;                     // [N, K+1]
  // wv = S_k*mu_k staged in the out buffer (64KB of 1MB); quad reads it before
  // softmax overwrites out — stream-ordered, safe.
  float* wv = out;

  for (int bs = 0; bs < 4; ++bs) {
    pivot_kernel<<<dim3(KC, 5), 512, 0, stream>>>(covs, S, Plbuf, ldp, bs);
    update_kernel<<<dim3(KC, 3), 512, 0, stream>>>(covs, S, Plbuf, bs);
  }
  pivot_kernel<<<dim3(KC, 5), 512, 0, stream>>>(covs, S, Plbuf, ldp, 4);
  w_kernel<<<KC, 256, 0, stream>>>(S, means, counts, n_points, ldp, cA, wv);
  quad_kernel<<<dim3(NPTS / NT, KC / KG), 256, 0, stream>>>(x, means, S, cA, wv, lp);
  softmax_kernel<<<NPTS, 64, 0, stream>>>(lp, n_points, out);
}

// Round 11
// 628.081 us; speedup vs baseline: 1.7371x; 1.0678x over previous
//
#include <hip/hip_runtime.h>
#include <math.h>

// StreamingDPM: probs = softmax([ -0.5*(D log2pi + logdet_k + quad_nk) + log_prior_k | log_new ])
// N=4096 D=256 K=64, out [N, K+1] fp32.
//
// ws layout (floats):
//   S    : K*D*D  (sweep result; holds -Sigma^{-1} after all steps)
//   cA   : K      (log_prior_k - 0.5*(D log2pi + logdet_k))
//   ldp  : 4*K    (per-block-step logdet partials)
//   lp   : N*K    (log-probs before softmax; ALIASED as Plbuf during sweep)
// wv (= S_k * mu_k, [K][D]) lives in the OUTPUT buffer temporarily (quad reads
// it before softmax overwrites out; stream-ordered, safe).
//
// Sweep schedule (per block step bs): pivot_kernel grid (K,5):
//   by<4  : deferred J-column writeback of step bs-1 (parallel, 64 rows each)
//   by==4 : register-resident sweep of the 64x64 pivot block (1 barrier/pivot)
// then update_kernel (K,3): trailing update of the 3 non-J column slices.
// (Cooperative single-kernel fusion measured WORSE: grid.sync ~70us each.)

#define DD 256
#define KC 64
#define NPTS 4096
#define NT 64
#define BB 64          // sweep block size
#define KG 4           // clusters per quad block

// ---------------- Kernel 1a: pivot sweep + deferred J-col writeback ----------
__global__ __launch_bounds__(512) void pivot_kernel(
    const float* __restrict__ covs, float* __restrict__ S,
    float* __restrict__ Plbuf, float* __restrict__ ldp, int bs)
{
  const int k = blockIdx.x;
  const int by = blockIdx.y;
  const int tid = threadIdx.x;
  float* Pb = Plbuf + (size_t)k * BB * BB;

  __shared__ __align__(16) float Tl[BB][BB + 4];
  __shared__ __align__(16) float pivc[2][BB];
  __shared__ __align__(16) float pivr[2][BB];

  if (by < 4) {
    // ---- deferred write of step bs-1's J columns (rows r0..r0+63):
    //  M[J,J] = -P^{-1} = Pb ;  M[I,J] = C*P^{-1} = -(C*Pb)
    if (bs == 0) return;
    const int j0p = (bs - 1) * BB;
    const int r0 = by * BB;
    const float* src = ((bs == 1) ? covs : (const float*)S) + (size_t)k * DD * DD;
    float* dst = S + (size_t)k * DD * DD;

    const int rr = tid >> 3;         // 0..63
    const int cc = (tid & 7) * 8;    // 0..56
    *reinterpret_cast<float4*>(&Tl[rr][cc]) =
        *reinterpret_cast<const float4*>(&Pb[rr * BB + cc]);
    *reinterpret_cast<float4*>(&Tl[rr][cc + 4]) =
        *reinterpret_cast<const float4*>(&Pb[rr * BB + cc + 4]);
    __syncthreads();

    const int r = r0 + rr;
    if (r0 == j0p) {
      // rows in J: direct copy of -P^{-1}
      *reinterpret_cast<float4*>(&dst[(size_t)r * DD + j0p + cc]) =
          *reinterpret_cast<const float4*>(&Tl[rr][cc]);
      *reinterpret_cast<float4*>(&dst[(size_t)r * DD + j0p + cc + 4]) =
          *reinterpret_cast<const float4*>(&Tl[rr][cc + 4]);
    } else {
      float Crow[BB];
      #pragma unroll
      for (int p = 0; p < BB; p += 4) {
        float4 cv = *reinterpret_cast<const float4*>(&src[(size_t)r * DD + j0p + p]);
        Crow[p] = cv.x; Crow[p + 1] = cv.y; Crow[p + 2] = cv.z; Crow[p + 3] = cv.w;
      }
      float acc[8] = {0.f, 0.f, 0.f, 0.f, 0.f, 0.f, 0.f, 0.f};
      #pragma unroll
      for (int p = 0; p < BB; ++p) {
        float4 t0 = *reinterpret_cast<const float4*>(&Tl[p][cc]);
        float4 t1 = *reinterpret_cast<const float4*>(&Tl[p][cc + 4]);
        acc[0] = fmaf(Crow[p], t0.x, acc[0]);
        acc[1] = fmaf(Crow[p], t0.y, acc[1]);
        acc[2] = fmaf(Crow[p], t0.z, acc[2]);
        acc[3] = fmaf(Crow[p], t0.w, acc[3]);
        acc[4] = fmaf(Crow[p], t1.x, acc[4]);
        acc[5] = fmaf(Crow[p], t1.y, acc[5]);
        acc[6] = fmaf(Crow[p], t1.z, acc[6]);
        acc[7] = fmaf(Crow[p], t1.w, acc[7]);
      }
      float4 o0 = {-acc[0], -acc[1], -acc[2], -acc[3]};
      float4 o1 = {-acc[4], -acc[5], -acc[6], -acc[7]};
      *reinterpret_cast<float4*>(&dst[(size_t)r * DD + j0p + cc]) = o0;
      *reinterpret_cast<float4*>(&dst[(size_t)r * DD + j0p + cc + 4]) = o1;
    }
    return;
  }

  if (bs == 4) return;  // flush launch: defer blocks only

  // ---- register-resident sweep of P = S[J,J] (step 0: from covs).
  // Thread owns row pr, cols pc..pc+7 in VGPRs for all 64 pivots; only the
  // pivot row/col is exchanged via double-buffered LDS. 1 barrier per pivot.
  const int j0 = bs * BB;
  const float* psrc = ((bs == 0) ? covs : (const float*)S) + (size_t)k * DD * DD;
  const int pr = tid >> 3;
  const int pc = (tid & 7) * 8;

  float v[8];
  {
    float4 a4 = *reinterpret_cast<const float4*>(&psrc[(size_t)(j0 + pr) * DD + j0 + pc]);
    float4 b4 = *reinterpret_cast<const float4*>(&psrc[(size_t)(j0 + pr) * DD + j0 + pc + 4]);
    v[0] = a4.x; v[1] = a4.y; v[2] = a4.z; v[3] = a4.w;
    v[4] = b4.x; v[5] = b4.y; v[6] = b4.z; v[7] = b4.w;
  }
  if (pc == 0) pivc[0][pr] = v[0];
  if (pr == 0) {
    #pragma unroll
    for (int e = 0; e < 8; ++e) pivr[0][pc + e] = v[e];
  }
  __syncthreads();

  float ld = 0.0f;
  #pragma unroll 1
  for (int p = 0; p < BB; ++p) {
    const int cur = p & 1, nxt = cur ^ 1;
    const float d = pivc[cur][p];
    const float inv_d = 1.0f / d;
    if (tid == 0) ld += logf(d);
    const float cr = pivc[cur][pr];
    float rw[8];
    *reinterpret_cast<float4*>(&rw[0]) = *reinterpret_cast<const float4*>(&pivr[cur][pc]);
    *reinterpret_cast<float4*>(&rw[4]) = *reinterpret_cast<const float4*>(&pivr[cur][pc + 4]);
    #pragma unroll
    for (int e = 0; e < 8; ++e) {
      float ge = fmaf(-inv_d * cr, rw[e], v[e]);         // general update
      if (pr == p)     ge = rw[e] * inv_d;               // pivot row
      if (pc + e == p) ge = (pr == p) ? -inv_d : cr * inv_d;  // pivot col/diag
      v[e] = ge;
    }
    if (p < BB - 1) {
      if (pr == p + 1) {
        #pragma unroll
        for (int e = 0; e < 8; ++e) pivr[nxt][pc + e] = v[e];
      }
      if (pc <= p + 1 && p + 1 < pc + 8) pivc[nxt][pr] = v[p + 1 - pc];
    }
    __syncthreads();
  }

  // store -P^{-1} for the update/deferred kernels (coalesced)
  float4 s0 = {v[0], v[1], v[2], v[3]};
  float4 s1 = {v[4], v[5], v[6], v[7]};
  *reinterpret_cast<float4*>(&Pb[pr * BB + pc]) = s0;
  *reinterpret_cast<float4*>(&Pb[pr * BB + pc + 4]) = s1;
  if (tid == 0) ldp[bs * KC + k] = ld;
}

// ---------------- Kernel 1b: trailing update of one non-J column slice ------
__global__ __launch_bounds__(512) void update_kernel(
    const float* __restrict__ covs, float* __restrict__ S,
    const float* __restrict__ Plbuf, int bs)
{
  const int k = blockIdx.x;
  const int si = blockIdx.y;
  const int t = si + (si >= bs ? 1 : 0);
  const int c0 = t * BB;
  const int j0 = bs * BB;
  const int tid = threadIdx.x;
  const float* src = ((bs == 0) ? covs : (const float*)S) + (size_t)k * DD * DD;
  float* dst = S + (size_t)k * DD * DD;

  __shared__ __align__(16) float Pl[BB][BB + 4];
  __shared__ __align__(16) float SJ[BB][BB + 4];
  __shared__ __align__(16) float Tl[BB][BB + 4];

  const float* Pb = Plbuf + (size_t)k * BB * BB;
  #pragma unroll
  for (int q = 0; q < 8; ++q) {
    int e = q * 512 + tid;
    int r = e >> 6, c = e & 63;
    Pl[r][c] = Pb[e];
    SJ[r][c] = src[(size_t)(j0 + r) * DD + c0 + c];
  }
  __syncthreads();

  // ---- T' = Pl * SJ  (thread: col c, 8 rows)
  {
    const int c = tid & 63;
    const int rg = (tid >> 6) * 8;
    float tv[8];
    #pragma unroll
    for (int r = 0; r < 8; ++r) tv[r] = 0.0f;
    for (int p = 0; p < BB; p += 4) {
      float s0 = SJ[p][c], s1 = SJ[p + 1][c], s2 = SJ[p + 2][c], s3 = SJ[p + 3][c];
      #pragma unroll
      for (int r = 0; r < 8; ++r) {
        float4 pv = *reinterpret_cast<const float4*>(&Pl[rg + r][p]);
        tv[r] = fmaf(pv.x, s0, fmaf(pv.y, s1, fmaf(pv.z, s2, fmaf(pv.w, s3, tv[r]))));
      }
    }
    #pragma unroll
    for (int r = 0; r < 8; ++r) Tl[rg + r][c] = tv[r];
  }
  __syncthreads();

  // ---- apply to this column slice (thread: row r, 32 cols)
  const int r = tid & 255;
  const int h = (tid >> 8) * 32;
  const bool inJ = (r >= j0) && (r < j0 + BB);  // wave-uniform
  if (inJ) {
    #pragma unroll
    for (int c = 0; c < 32; c += 4) {
      float4 tv4 = *reinterpret_cast<const float4*>(&Tl[r - j0][h + c]);
      float4 o = {-tv4.x, -tv4.y, -tv4.z, -tv4.w};
      *reinterpret_cast<float4*>(&dst[(size_t)r * DD + c0 + h + c]) = o;
    }
  } else {
    float Crow[BB];
    #pragma unroll
    for (int p = 0; p < BB; p += 4) {
      float4 cv = *reinterpret_cast<const float4*>(&src[(size_t)r * DD + j0 + p]);
      Crow[p] = cv.x; Crow[p + 1] = cv.y; Crow[p + 2] = cv.z; Crow[p + 3] = cv.w;
    }
    #pragma unroll
    for (int c = 0; c < 32; c += 4) {
      float4 acc = *reinterpret_cast<const float4*>(&src[(size_t)r * DD + c0 + h + c]);
      #pragma unroll
      for (int p = 0; p < BB; ++p) {
        float4 tv4 = *reinterpret_cast<const float4*>(&Tl[p][h + c]);
        acc.x = fmaf(Crow[p], tv4.x, acc.x);
        acc.y = fmaf(Crow[p], tv4.y, acc.y);
        acc.z = fmaf(Crow[p], tv4.z, acc.z);
        acc.w = fmaf(Crow[p], tv4.w, acc.w);
      }
      *reinterpret_cast<float4*>(&dst[(size_t)r * DD + c0 + h + c]) = acc;
    }
  }
}

// ---------------- Kernel 1c: wv_k = S_k * mu_k ; cA assembly -----------------
__global__ __launch_bounds__(256) void w_kernel(
    const float* __restrict__ S, const float* __restrict__ means,
    const float* __restrict__ counts, const int* __restrict__ n_points_p,
    const float* __restrict__ ldp, float* __restrict__ cA,
    float* __restrict__ wv)
{
  const int k = blockIdx.x;
  const int tid = threadIdx.x;
  if (tid == 0) {
    float denom = (float)(*n_points_p) + 1.0f;  // ALPHA = 1
    float ld = ldp[k] + ldp[KC + k] + ldp[2 * KC + k] + ldp[3 * KC + k];
    // D*log(2*pi) = 256 * 1.8378770664093453
    cA[k] = logf(counts[k] / denom) - 0.5f * (470.49652900079047f + ld);
  }
  const float* Sk = S + (size_t)k * DD * DD;
  __shared__ float mus[DD];
  mus[tid] = means[(size_t)k * DD + tid];
  __syncthreads();
  float a0 = 0.f, a1 = 0.f, a2 = 0.f, a3 = 0.f;
  for (int j = 0; j < DD; j += 4) {
    a0 = fmaf(Sk[(size_t)(j + 0) * DD + tid], mus[j + 0], a0);
    a1 = fmaf(Sk[(size_t)(j + 1) * DD + tid], mus[j + 1], a1);
    a2 = fmaf(Sk[(size_t)(j + 2) * DD + tid], mus[j + 2], a2);
    a3 = fmaf(Sk[(size_t)(j + 3) * DD + tid], mus[j + 3], a3);
  }
  wv[(size_t)k * DD + tid] = (a0 + a1) + (a2 + a3);
}

// ---------------- Kernel 2: quad, wave-private barrier-free inner loop -------
// dev^T S dev = sum_j (x_j - mu_j) * ((X*S)_nj - wv_j)   (S symmetric).
// 8n x 8j register tile. Each wave reads ONLY S columns [wave*64, wave*64+64)
// (tj = tid>>3 spans 8 values per wave), so S is staged in a WAVE-PRIVATE,
// double-buffered LDS strip Pw[wave][2][4][68] with a 1-chunk-ahead register
// prefetch. Intra-wave LDS ordering is by lgkmcnt: ZERO __syncthreads in the
// 256-iteration inner loop (r7/r10 had 64 block barriers per k = the ~30%
// VALU idle). Barriers only at k boundaries (3/k). LDS = 64+8.5+2+1 = 75.5 KB
// -> 2 blocks/CU. qred aliases Pw.
__global__ __launch_bounds__(256) void quad_kernel(
    const float* __restrict__ X, const float* __restrict__ means,
    const float* __restrict__ S, const float* __restrict__ cA,
    const float* __restrict__ wv, float* __restrict__ lp)
{
  __shared__ __align__(16) float XT[DD][NT];        // (i,r) at XT[i][r ^ (((i>>2)&15)<<2)]
  __shared__ __align__(16) float Pw[4][2][4][68];   // wave-private S strips; qred alias
  __shared__ __align__(16) float muw[2][DD];        // mu_k, wv_k
  __shared__ __align__(16) float lpb[KG][NT];       // results, flushed at end

  const int tid = threadIdx.x;
  const int n0 = blockIdx.x * NT;
  const int k0 = blockIdx.y * KG;

  // stage X tile transposed + swizzled (once per block)
  #pragma unroll
  for (int q = 0; q < 16; ++q) {
    int f = q * 1024 + tid * 4;
    int r = f >> 8;
    int c = f & 255;
    float4 xv = *reinterpret_cast<const float4*>(X + (size_t)(n0 + r) * DD + c);
    int rs = r ^ (((c >> 2) & 15) << 2);
    XT[c + 0][rs] = xv.x;
    XT[c + 1][rs] = xv.y;
    XT[c + 2][rs] = xv.z;
    XT[c + 3][rs] = xv.w;
  }

  const int tn = tid & 7;          // n sub-tile: rows tn*8 .. +7
  const int tj = tid >> 3;         // j sub-tile: cols tj*8 .. +7
  const int wid = tid >> 6;        // wave id 0..3
  const int lane = tid & 63;
  const int g = (tid >> 3) & 7;    // tj within wave
  const int srow = lane >> 4;      // staging row within 4-row chunk
  const int scol = (lane & 15) * 4;// staging col (float4)

  #pragma unroll 1
  for (int kk = 0; kk < KG; ++kk) {
    const int k = k0 + kk;
    const float* Skw = S + (size_t)k * DD * DD + wid * 64;  // wave's col slice

    __syncthreads();  // prev k's qred readers done (Pw aliased); XT staged
    muw[0][tid] = means[(size_t)k * DD + tid];
    muw[1][tid] = wv[(size_t)k * DD + tid];

    // prologue: chunk 0 -> LDS buf 0; chunk 1 -> prefetch regs
    float4 st = *reinterpret_cast<const float4*>(Skw + (size_t)srow * DD + scol);
    *reinterpret_cast<float4*>(&Pw[wid][0][srow][scol]) = st;
    st = *reinterpret_cast<const float4*>(Skw + (size_t)(4 + srow) * DD + scol);

    float y[8][8];
    #pragma unroll
    for (int a = 0; a < 8; ++a)
      #pragma unroll
      for (int b = 0; b < 8; ++b) y[a][b] = 0.0f;

    #pragma unroll 1
    for (int ct = 0; ct < 64; ++ct) {
      const int cur = ct & 1;
      #pragma unroll
      for (int il = 0; il < 4; ++il) {
        const int i = ct * 4 + il;
        const int sw = ((i >> 2) & 15) << 2;
        float xv[8], pv[8];
        *reinterpret_cast<float4*>(&xv[0]) =
            *reinterpret_cast<const float4*>(&XT[i][(tn * 8) ^ sw]);
        *reinterpret_cast<float4*>(&xv[4]) =
            *reinterpret_cast<const float4*>(&XT[i][(tn * 8 + 4) ^ sw]);
        *reinterpret_cast<float4*>(&pv[0]) =
            *reinterpret_cast<const float4*>(&Pw[wid][cur][il][g * 8]);
        *reinterpret_cast<float4*>(&pv[4]) =
            *reinterpret_cast<const float4*>(&Pw[wid][cur][il][g * 8 + 4]);
        #pragma unroll
        for (int a = 0; a < 8; ++a)
          #pragma unroll
          for (int b = 0; b < 8; ++b)
            y[a][b] = fmaf(xv[a], pv[b], y[a][b]);
      }
      if (ct < 63) {
        // publish chunk ct+1 into the other buffer (wave-private, no barrier);
        // prefetch chunk ct+2 into regs (stays in flight across next 4 ils)
        *reinterpret_cast<float4*>(&Pw[wid][cur ^ 1][srow][scol]) = st;
        const int cnx = (ct + 2 < 64) ? (ct + 2) : 63;
        st = *reinterpret_cast<const float4*>(
            Skw + (size_t)(cnx * 4 + srow) * DD + scol);
      }
    }
    __syncthreads();  // muw visible; all waves done with Pw before qred reuse

    // epilogue: q'[n] = sum_j (x[n,j]-mu_j) * (y[n,j]-wv_j), partial over 8 j
    float s[8];
    #pragma unroll
    for (int a = 0; a < 8; ++a) s[a] = 0.0f;
    #pragma unroll
    for (int b = 0; b < 8; ++b) {
      const int j = tj * 8 + b;
      const int swj = ((j >> 2) & 15) << 2;
      float dv[8];
      *reinterpret_cast<float4*>(&dv[0]) =
          *reinterpret_cast<const float4*>(&XT[j][(tn * 8) ^ swj]);
      *reinterpret_cast<float4*>(&dv[4]) =
          *reinterpret_cast<const float4*>(&XT[j][(tn * 8 + 4) ^ swj]);
      const float mj = muw[0][j];
      const float wj = muw[1][j];
      #pragma unroll
      for (int a = 0; a < 8; ++a)
        s[a] = fmaf(dv[a] - mj, y[a][b] - wj, s[a]);
    }

    float* qred = &Pw[0][0][0][0];  // 2048 floats needed; Pw (2176) dead now
    *reinterpret_cast<float4*>(&qred[tj * 64 + tn * 8]) =
        *reinterpret_cast<const float4*>(&s[0]);
    *reinterpret_cast<float4*>(&qred[tj * 64 + tn * 8 + 4]) =
        *reinterpret_cast<const float4*>(&s[4]);
    __syncthreads();
    if (tid < 64) {
      float qa = 0.f, qb = 0.f, qc = 0.f, qd = 0.f;
      #pragma unroll
      for (int t = 0; t < 32; t += 4) {
        qa += qred[(t + 0) * 64 + tid];
        qb += qred[(t + 1) * 64 + tid];
        qc += qred[(t + 2) * 64 + tid];
        qd += qred[(t + 3) * 64 + tid];
      }
      // q' = dev^T S dev = -quad  ->  lp = cA + 0.5*q'
      lpb[kk][tid] = fmaf(0.5f, (qa + qb) + (qc + qd), cA[k]);
    }
  }

  // lp flush: one float4 of 4 k-values per point row
  __syncthreads();
  if (tid < 64) {
    float4 o = {lpb[0][tid], lpb[1][tid], lpb[2][tid], lpb[3][tid]};
    *reinterpret_cast<float4*>(&lp[(size_t)(n0 + tid) * KC + k0]) = o;
  }
}

// ---------------- Kernel 3: row softmax over K+1 = 65 entries -----------------
__global__ __launch_bounds__(64) void softmax_kernel(
    const float* __restrict__ lp, const int* __restrict__ n_points_p,
    float* __restrict__ out)
{
  const int n = blockIdx.x;
  const int l = threadIdx.x;
  const float denom = (float)(*n_points_p) + 1.0f;
  const float log_new = -logf(denom);  // log(ALPHA/denom), ALPHA=1

  float v = lp[(size_t)n * KC + l];
  float m = v;
  #pragma unroll
  for (int off = 32; off > 0; off >>= 1) m = fmaxf(m, __shfl_xor(m, off, 64));
  m = fmaxf(m, log_new);

  float e = expf(v - m);
  float s = e;
  #pragma unroll
  for (int off = 32; off > 0; off >>= 1) s += __shfl_xor(s, off, 64);
  float enew = expf(log_new - m);
  s += enew;

  out[(size_t)n * (KC + 1) + l] = e / s;
  if (l == 0) out[(size_t)n * (KC + 1) + KC] = enew / s;
}

extern "C" void kernel_launch(void* const* d_in, const int* in_sizes, int n_in,
                              void* d_out, int out_size, void* d_ws, size_t ws_size,
                              hipStream_t stream)
{
  const float* x       = (const float*)d_in[0];  // [N, D]
  const float* means   = (const float*)d_in[1];  // [K, D]
  const float* covs    = (const float*)d_in[2];  // [K, D, D]
  const float* counts  = (const float*)d_in[3];  // [K]
  const int*   n_points = (const int*)d_in[4];   // scalar

  float* S   = (float*)d_ws;                      // K*D*D
  float* cA  = S + (size_t)KC * DD * DD;          // K
  float* ldp = cA + KC;                           // 4*K
  float* lp  = ldp + 4 * KC;                      // N*K
  float* Plbuf = lp;  // alias: Plbuf (K*64*64 = N*K floats) used only during
                      // sweep; lp written only by quad afterwards.
  float* out = (float*)d_out;                     // [N, K+1]
  // wv = S_k*mu_k staged in the out buffer (64KB of 1MB); quad reads it before
  // softmax overwrites out — stream-ordered, safe.
  float* wv = out;

  for (int bs = 0; bs < 4; ++bs) {
    pivot_kernel<<<dim3(KC, 5), 512, 0, stream>>>(covs, S, Plbuf, ldp, bs);
    update_kernel<<<dim3(KC, 3), 512, 0, stream>>>(covs, S, Plbuf, bs);
  }
  pivot_kernel<<<dim3(KC, 5), 512, 0, stream>>>(covs, S, Plbuf, ldp, 4);
  w_kernel<<<KC, 256, 0, stream>>>(S, means, counts, n_points, ldp, cA, wv);
  quad_kernel<<<dim3(NPTS / NT, KC / KG), 256, 0, stream>>>(x, means, S, cA, wv, lp);
  softmax_kernel<<<NPTS, 64, 0, stream>>>(lp, n_points, out);
}